// Round 5
// baseline (504.861 us; speedup 1.0000x reference)
//
#include <hip/hip_runtime.h>
#include <hip/hip_bf16.h>

// GIN layer: out = relu(((1+eps)*x + segment_sum(x[src], dst)) @ W1 + b1) @ W2 + b2
// N=50000 nodes, E=1.6M edges, D=128.

#define N_NODES 50000
#define N_EDGES 1600000
#define D 128

#define NB_H 128                 // histogram blocks (block-private hists)
#define CHUNK (N_EDGES / NB_H)   // 12500 edges per block
#define HPAD 50048               // ints per private hist; 50048*4 % 128 == 0

typedef __attribute__((ext_vector_type(8))) short short8;
typedef __attribute__((ext_vector_type(4))) float float4v;

__device__ inline unsigned short f2b(float f) {
    unsigned u = __builtin_bit_cast(unsigned, f);
    u = u + 0x7fffu + ((u >> 16) & 1u);  // RNE
    return (unsigned short)(u >> 16);
}
__device__ inline float b2f_lo(unsigned u) { return __builtin_bit_cast(float, u << 16); }
__device__ inline float b2f_hi(unsigned u) { return __builtin_bit_cast(float, u & 0xffff0000u); }

// ---------------- edge dtype detection ----------------
__global__ void k_detect(const int* __restrict__ ei, int* __restrict__ flag) {
    __shared__ int nz;
    if (threadIdx.x == 0) nz = 0;
    __syncthreads();
    int v = ei[threadIdx.x * 2 + 1];
    if (v != 0) atomicAdd(&nz, 1);
    __syncthreads();
    if (threadIdx.x == 0) *flag = (nz == 0) ? 1 : 0;  // 1 => int64 layout
}

// ---------------- x f32 -> packed bf16 ----------------
__global__ __launch_bounds__(256) void k_cvt(const float* __restrict__ x,
                                             unsigned short* __restrict__ xb) {
    int i = blockIdx.x * blockDim.x + threadIdx.x;
    if (i >= N_NODES * (D / 4)) return;
    float4 v = ((const float4*)x)[i];
    ushort4 o;
    o.x = f2b(v.x); o.y = f2b(v.y); o.z = f2b(v.z); o.w = f2b(v.w);
    ((ushort4*)xb)[i] = o;
}

// ---------------- zero the private-histogram matrix ----------------
__global__ __launch_bounds__(256) void k_zero_cnt(int* __restrict__ cnt) {
    const size_t total4 = (size_t)NB_H * HPAD / 4;  // int4 count
    size_t i = (size_t)blockIdx.x * blockDim.x + threadIdx.x;
    size_t stride = (size_t)gridDim.x * blockDim.x;
    int4 z = make_int4(0, 0, 0, 0);
    for (; i < total4; i += stride) ((int4*)cnt)[i] = z;
}

// ---------------- block-private histogram + per-edge local rank ----------------
// Block b owns cnt[b][*]; workgroup-scope atomics can stay in the XCD's L2.
__global__ __launch_bounds__(1024) void k_hist_rank(const int* __restrict__ ei,
                                                    const int* __restrict__ flag,
                                                    int* __restrict__ cnt,
                                                    int* __restrict__ rank) {
    int b = blockIdx.x;
    int wide = *flag;
    int* hist = cnt + (size_t)b * HPAD;
    int e0 = b * CHUNK;
    for (int i = threadIdx.x; i < CHUNK; i += 1024) {
        int e = e0 + i;
        long long di = (long long)N_EDGES + e;
        int d = wide ? ei[di * 2] : ei[di];
        int r = 0;
        if ((unsigned)d < (unsigned)N_NODES)
            r = __hip_atomic_fetch_add(&hist[d], 1, __ATOMIC_RELAXED,
                                       __HIP_MEMORY_SCOPE_WORKGROUP);
        rank[e] = r;  // coalesced
    }
}

// ---------------- column scan: cnt[b][d] -> exclusive prefix over b; deg[d]=total ----
__global__ __launch_bounds__(512) void k_colscan(int* __restrict__ cnt,
                                                 int* __restrict__ deg) {
    int d = blockIdx.x * 512 + threadIdx.x;
    if (d >= N_NODES) return;
    int run = 0;
    #pragma unroll 4
    for (int b = 0; b < NB_H; ++b) {
        size_t idx = (size_t)b * HPAD + d;
        int v = cnt[idx];
        cnt[idx] = run;
        run += v;
    }
    deg[d] = run;
}

// ---------------- multi-block exclusive scan over deg ----------------
__global__ __launch_bounds__(512) void k_scan1(const int* __restrict__ deg,
                                               int* __restrict__ offsets,
                                               int* __restrict__ bsum) {
    __shared__ int tmp[512];
    int t = threadIdx.x;
    int gid = blockIdx.x * 512 + t;
    int v = (gid < N_NODES) ? deg[gid] : 0;
    tmp[t] = v;
    __syncthreads();
    for (int off = 1; off < 512; off <<= 1) {
        int u = (t >= off) ? tmp[t - off] : 0;
        __syncthreads();
        tmp[t] += u;
        __syncthreads();
    }
    if (gid < N_NODES) offsets[gid] = tmp[t] - v;
    if (t == 511) bsum[blockIdx.x] = tmp[511];
}

__global__ __launch_bounds__(128) void k_scan2(int* __restrict__ bsum, int nb) {
    __shared__ int tmp[128];
    int t = threadIdx.x;
    int orig = (t < nb) ? bsum[t] : 0;
    tmp[t] = orig;
    __syncthreads();
    for (int off = 1; off < 128; off <<= 1) {
        int u = (t >= off) ? tmp[t - off] : 0;
        __syncthreads();
        tmp[t] += u;
        __syncthreads();
    }
    if (t < nb) bsum[t] = tmp[t] - orig;
}

__global__ __launch_bounds__(512) void k_scan3(int* __restrict__ offsets,
                                               const int* __restrict__ bsum) {
    int gid = blockIdx.x * 512 + threadIdx.x;
    if (gid < N_NODES) offsets[gid] += bsum[blockIdx.x];
}

// ---------------- CSR place (no atomics): pos = offsets[d] + cnt[b][d] + rank[e] ----
__global__ __launch_bounds__(1024) void k_place(const int* __restrict__ ei,
                                                const int* __restrict__ flag,
                                                const int* __restrict__ offsets,
                                                const int* __restrict__ cnt,
                                                const int* __restrict__ rank,
                                                int* __restrict__ srcs) {
    int b = blockIdx.x;
    int wide = *flag;
    const int* hist = cnt + (size_t)b * HPAD;
    int e0 = b * CHUNK;
    for (int i = threadIdx.x; i < CHUNK; i += 1024) {
        int e = e0 + i;
        int s = wide ? ei[(long long)e * 2] : ei[e];
        long long di = (long long)N_EDGES + e;
        int d = wide ? ei[di * 2] : ei[di];
        if ((unsigned)d < (unsigned)N_NODES && (unsigned)s < (unsigned)N_NODES)
            srcs[offsets[d] + hist[d] + rank[e]] = s;
    }
}

// ---------------- gather, XCD-sliced columns ----------------
// Block: 256 threads = 4 waves = 4 nodes; slice c = blockIdx%8 (XCD heuristic).
// Each wave: lanes (g=lane>>3 neighbor group, u=lane&7 uint col of the 16-col slice).
__global__ __launch_bounds__(256) void k_gather(const float* __restrict__ x,
                                                const unsigned short* __restrict__ xb,
                                                const int* __restrict__ srcs,
                                                const int* __restrict__ offsets,
                                                const int* __restrict__ deg,
                                                float* __restrict__ agg) {
    int b = blockIdx.x;
    int c = b & 7;                       // column slice 0..7 (16 cols each)
    int node = (b >> 3) * 4 + (threadIdx.x >> 6);
    int lane = threadIdx.x & 63;
    int g = lane >> 3;                   // neighbor group 0..7
    int u = lane & 7;                    // uint (2 bf16 cols) within slice
    if (node >= N_NODES) return;
    int beg = offsets[node];
    int end = beg + deg[node];
    const unsigned* xr = (const unsigned*)xb;
    float ax = 0.f, ay = 0.f;
    int j = beg + g;
    for (; j + 8 < end; j += 16) {
        int s0 = __builtin_nontemporal_load(&srcs[j]);
        int s1 = __builtin_nontemporal_load(&srcs[j + 8]);
        unsigned a0 = xr[(size_t)s0 * 64 + c * 8 + u];   // row = 64 uints (128 bf16)
        unsigned a1 = xr[(size_t)s1 * 64 + c * 8 + u];
        ax += b2f_lo(a0); ay += b2f_hi(a0);
        ax += b2f_lo(a1); ay += b2f_hi(a1);
    }
    if (j < end) {
        int s0 = __builtin_nontemporal_load(&srcs[j]);
        unsigned a0 = xr[(size_t)s0 * 64 + c * 8 + u];
        ax += b2f_lo(a0); ay += b2f_hi(a0);
    }
    // reduce across the 8 neighbor groups (lanes xor 8,16,32)
    #pragma unroll
    for (int m = 8; m <= 32; m <<= 1) {
        ax += __shfl_xor(ax, m, 64);
        ay += __shfl_xor(ay, m, 64);
    }
    if (g == 0) {
        float2 xs = ((const float2*)x)[(size_t)node * 64 + c * 8 + u];
        float2 o;
        o.x = fmaf(1.001f, xs.x, ax);
        o.y = fmaf(1.001f, xs.y, ay);
        ((float2*)agg)[(size_t)node * 64 + c * 8 + u] = o;
    }
}

// ---------------- bf16 MFMA GEMM: out[M,128] = A[M,128] @ W[128,128] + b ----------------
#define LPAD 136
template <int RELU>
__global__ __launch_bounds__(256, 2) void k_gemm(const float* __restrict__ A,
                                                 const float* __restrict__ Wg,
                                                 const float* __restrict__ bias,
                                                 float* __restrict__ out, int M) {
    __shared__ short Al[128 * LPAD];   // [row][k]
    __shared__ short Wt[128 * LPAD];   // [n][k]  (transposed W)
    __shared__ float bl[128];

    int t = threadIdx.x;
    int row0 = blockIdx.x * 128;

    const float4* A4 = (const float4*)A;
    #pragma unroll
    for (int i = 0; i < 16; ++i) {
        int idx = i * 256 + t;
        int r = idx >> 5;
        int c4 = idx & 31;
        float4 v = make_float4(0.f, 0.f, 0.f, 0.f);
        if (row0 + r < M) v = A4[(size_t)(row0 + r) * 32 + c4];
        ushort4 o;
        o.x = f2b(v.x); o.y = f2b(v.y); o.z = f2b(v.z); o.w = f2b(v.w);
        *(ushort4*)&Al[r * LPAD + c4 * 4] = o;
    }
    const float4* W4 = (const float4*)Wg;
    #pragma unroll
    for (int i = 0; i < 16; ++i) {
        int idx = i * 256 + t;
        int k = idx >> 5;
        int n4 = idx & 31;
        float4 v = W4[k * 32 + n4];
        Wt[(n4 * 4 + 0) * LPAD + k] = (short)f2b(v.x);
        Wt[(n4 * 4 + 1) * LPAD + k] = (short)f2b(v.y);
        Wt[(n4 * 4 + 2) * LPAD + k] = (short)f2b(v.z);
        Wt[(n4 * 4 + 3) * LPAD + k] = (short)f2b(v.w);
    }
    if (t < 32) ((float4*)bl)[t] = ((const float4*)bias)[t];
    __syncthreads();

    int wave = t >> 6;
    int lane = t & 63;
    int quad = lane >> 4;
    int l16 = lane & 15;
    int rowbase = wave * 32;

    float4v acc[2][8];
    #pragma unroll
    for (int mt = 0; mt < 2; ++mt)
        #pragma unroll
        for (int nt = 0; nt < 8; ++nt)
            acc[mt][nt] = (float4v){0.f, 0.f, 0.f, 0.f};

    #pragma unroll
    for (int kc = 0; kc < 4; ++kc) {
        int koff = kc * 32 + quad * 8;
        short8 a0 = *(const short8*)&Al[(rowbase + l16) * LPAD + koff];
        short8 a1 = *(const short8*)&Al[(rowbase + 16 + l16) * LPAD + koff];
        #pragma unroll
        for (int nt = 0; nt < 8; ++nt) {
            short8 bfr = *(const short8*)&Wt[(nt * 16 + l16) * LPAD + koff];
            acc[0][nt] = __builtin_amdgcn_mfma_f32_16x16x32_bf16(a0, bfr, acc[0][nt], 0, 0, 0);
            acc[1][nt] = __builtin_amdgcn_mfma_f32_16x16x32_bf16(a1, bfr, acc[1][nt], 0, 0, 0);
        }
    }

    #pragma unroll
    for (int mt = 0; mt < 2; ++mt) {
        int rloc = rowbase + mt * 16 + quad * 4;
        #pragma unroll
        for (int nt = 0; nt < 8; ++nt) {
            int col = nt * 16 + l16;
            float bv = bl[col];
            #pragma unroll
            for (int r = 0; r < 4; ++r) {
                int grow = row0 + rloc + r;
                if (grow < M) {
                    float v = acc[mt][nt][r] + bv;
                    if (RELU) v = fmaxf(v, 0.f);
                    out[(size_t)grow * 128 + col] = v;
                }
            }
        }
    }
}

extern "C" void kernel_launch(void* const* d_in, const int* in_sizes, int n_in,
                              void* d_out, int out_size, void* d_ws, size_t ws_size,
                              hipStream_t stream) {
    const float* x  = (const float*)d_in[0];
    const int*   ei = (const int*)d_in[1];
    const float* W1 = (const float*)d_in[2];
    const float* b1 = (const float*)d_in[3];
    const float* W2 = (const float*)d_in[4];
    const float* b2 = (const float*)d_in[5];
    float* out = (float*)d_out;

    // workspace layout (bytes):
    //   [0, 25,624,576)        cnt matrix (alias: agg [0,25.6e6) written later by gather)
    //   [25,700,000, 51,300,000) h  (aliases: rank @25.7e6 (6.4MB), srcs @32.1e6 (6.4MB),
    //                                xb @38.5e6 (12.8MB) — all dead before gemm1 writes h)
    //   [51,300,000 ...) deg, offsets, bsum, flag
    char* ws = (char*)d_ws;
    int*            cnt     = (int*)  (ws);
    float*          agg     = (float*)(ws);
    float*          h       = (float*)(ws + 25700000);
    int*            rank    = (int*)  (ws + 25700000);
    int*            srcs    = (int*)  (ws + 32100000);
    unsigned short* xb      = (unsigned short*)(ws + 38500000);
    int*            deg     = (int*)  (ws + 51300000);
    int*            offsets = (int*)  (ws + 51500000);
    int*            bsum    = (int*)  (ws + 51700000);
    int*            flag    = (int*)  (ws + 51710000);

    const int NB_SCAN = (N_NODES + 511) / 512;  // 98

    k_detect<<<1, 256, 0, stream>>>(ei, flag);
    k_cvt<<<(N_NODES * (D / 4) + 255) / 256, 256, 0, stream>>>(x, xb);
    k_zero_cnt<<<1024, 256, 0, stream>>>(cnt);
    k_hist_rank<<<NB_H, 1024, 0, stream>>>(ei, flag, cnt, rank);
    k_colscan<<<NB_SCAN, 512, 0, stream>>>(cnt, deg);
    k_scan1<<<NB_SCAN, 512, 0, stream>>>(deg, offsets, bsum);
    k_scan2<<<1, 128, 0, stream>>>(bsum, NB_SCAN);
    k_scan3<<<NB_SCAN, 512, 0, stream>>>(offsets, bsum);
    k_place<<<NB_H, 1024, 0, stream>>>(ei, flag, offsets, cnt, rank, srcs);
    k_gather<<<(N_NODES / 4) * 8, 256, 0, stream>>>(x, xb, srcs, offsets, deg, agg);

    int gblocks = (N_NODES + 127) / 128;  // 391
    k_gemm<1><<<gblocks, 256, 0, stream>>>(agg, W1, b1, h, N_NODES);
    k_gemm<0><<<gblocks, 256, 0, stream>>>(h, W2, b2, out, N_NODES);
}

// Round 6
// 368.640 us; speedup vs baseline: 1.3695x; 1.3695x over previous
//
#include <hip/hip_runtime.h>
#include <hip/hip_bf16.h>

// GIN layer: out = relu(((1+eps)*x + segment_sum(x[src], dst)) @ W1 + b1) @ W2 + b2
// N=50000 nodes, E=1.6M edges, D=128.

#define N_NODES 50000
#define N_EDGES 1600000
#define D 128

#define NB_H 64                  // histogram blocks (block-private hists)
#define CHUNK (N_EDGES / NB_H)   // 25000 edges per block
#define HPAD 50048               // ints per private hist; 50048*4 % 128 == 0

typedef __attribute__((ext_vector_type(8))) short short8;
typedef __attribute__((ext_vector_type(4))) float float4v;

__device__ inline unsigned short f2b(float f) {
    unsigned u = __builtin_bit_cast(unsigned, f);
    u = u + 0x7fffu + ((u >> 16) & 1u);  // RNE
    return (unsigned short)(u >> 16);
}
__device__ inline float b2f_lo(unsigned u) { return __builtin_bit_cast(float, u << 16); }
__device__ inline float b2f_hi(unsigned u) { return __builtin_bit_cast(float, u & 0xffff0000u); }

// ---------------- edge dtype detection ----------------
__global__ void k_detect(const int* __restrict__ ei, int* __restrict__ flag) {
    __shared__ int nz;
    if (threadIdx.x == 0) nz = 0;
    __syncthreads();
    int v = ei[threadIdx.x * 2 + 1];
    if (v != 0) atomicAdd(&nz, 1);
    __syncthreads();
    if (threadIdx.x == 0) *flag = (nz == 0) ? 1 : 0;  // 1 => int64 layout
}

// ---------------- x f32 -> packed bf16 ----------------
__global__ __launch_bounds__(256) void k_cvt(const float* __restrict__ x,
                                             unsigned short* __restrict__ xb) {
    int i = blockIdx.x * blockDim.x + threadIdx.x;
    if (i >= N_NODES * (D / 4)) return;
    float4 v = ((const float4*)x)[i];
    ushort4 o;
    o.x = f2b(v.x); o.y = f2b(v.y); o.z = f2b(v.z); o.w = f2b(v.w);
    ((ushort4*)xb)[i] = o;
}

// ---------------- zero the private-histogram matrix ----------------
__global__ __launch_bounds__(256) void k_zero_cnt(int* __restrict__ cnt) {
    const size_t total4 = (size_t)NB_H * HPAD / 4;  // int4 count
    size_t i = (size_t)blockIdx.x * blockDim.x + threadIdx.x;
    size_t stride = (size_t)gridDim.x * blockDim.x;
    int4 z = make_int4(0, 0, 0, 0);
    for (; i < total4; i += stride) ((int4*)cnt)[i] = z;
}

// ---------------- block-private histogram + per-edge local rank ----------------
// Block b owns cnt[b][*]; workgroup-scope atomics can stay in the XCD's L2.
__global__ __launch_bounds__(1024) void k_hist_rank(const int* __restrict__ ei,
                                                    const int* __restrict__ flag,
                                                    int* __restrict__ cnt,
                                                    int* __restrict__ rank) {
    int b = blockIdx.x;
    int wide = *flag;
    int* hist = cnt + (size_t)b * HPAD;
    int e0 = b * CHUNK;
    for (int i = threadIdx.x; i < CHUNK; i += 1024) {
        int e = e0 + i;
        long long di = (long long)N_EDGES + e;
        int d = wide ? ei[di * 2] : ei[di];
        int r = 0;
        if ((unsigned)d < (unsigned)N_NODES)
            r = __hip_atomic_fetch_add(&hist[d], 1, __ATOMIC_RELAXED,
                                       __HIP_MEMORY_SCOPE_WORKGROUP);
        rank[e] = r;  // coalesced
    }
}

// ---------------- column scan: cnt[b][d] -> exclusive prefix over b; deg[d]=total ----
__global__ __launch_bounds__(512) void k_colscan(int* __restrict__ cnt,
                                                 int* __restrict__ deg) {
    int d = blockIdx.x * 512 + threadIdx.x;
    if (d >= N_NODES) return;
    int run = 0;
    #pragma unroll 4
    for (int b = 0; b < NB_H; ++b) {
        size_t idx = (size_t)b * HPAD + d;
        int v = cnt[idx];
        cnt[idx] = run;
        run += v;
    }
    deg[d] = run;
}

// ---------------- multi-block exclusive scan over deg ----------------
__global__ __launch_bounds__(512) void k_scan1(const int* __restrict__ deg,
                                               int* __restrict__ offsets,
                                               int* __restrict__ bsum) {
    __shared__ int tmp[512];
    int t = threadIdx.x;
    int gid = blockIdx.x * 512 + t;
    int v = (gid < N_NODES) ? deg[gid] : 0;
    tmp[t] = v;
    __syncthreads();
    for (int off = 1; off < 512; off <<= 1) {
        int u = (t >= off) ? tmp[t - off] : 0;
        __syncthreads();
        tmp[t] += u;
        __syncthreads();
    }
    if (gid < N_NODES) offsets[gid] = tmp[t] - v;
    if (t == 511) bsum[blockIdx.x] = tmp[511];
}

__global__ __launch_bounds__(128) void k_scan2(int* __restrict__ bsum, int nb) {
    __shared__ int tmp[128];
    int t = threadIdx.x;
    int orig = (t < nb) ? bsum[t] : 0;
    tmp[t] = orig;
    __syncthreads();
    for (int off = 1; off < 128; off <<= 1) {
        int u = (t >= off) ? tmp[t - off] : 0;
        __syncthreads();
        tmp[t] += u;
        __syncthreads();
    }
    if (t < nb) bsum[t] = tmp[t] - orig;
}

__global__ __launch_bounds__(512) void k_scan3(int* __restrict__ offsets,
                                               const int* __restrict__ bsum) {
    int gid = blockIdx.x * 512 + threadIdx.x;
    if (gid < N_NODES) offsets[gid] += bsum[blockIdx.x];
}

// ---------------- CSR place (no atomics): pos = offsets[d] + cnt[b][d] + rank[e] ----
__global__ __launch_bounds__(1024) void k_place(const int* __restrict__ ei,
                                                const int* __restrict__ flag,
                                                const int* __restrict__ offsets,
                                                const int* __restrict__ cnt,
                                                const int* __restrict__ rank,
                                                int* __restrict__ srcs) {
    int b = blockIdx.x;
    int wide = *flag;
    const int* hist = cnt + (size_t)b * HPAD;
    int e0 = b * CHUNK;
    for (int i = threadIdx.x; i < CHUNK; i += 1024) {
        int e = e0 + i;
        int s = wide ? ei[(long long)e * 2] : ei[e];
        long long di = (long long)N_EDGES + e;
        int d = wide ? ei[di * 2] : ei[di];
        if ((unsigned)d < (unsigned)N_NODES && (unsigned)s < (unsigned)N_NODES)
            srcs[offsets[d] + hist[d] + rank[e]] = s;
    }
}

// ---------------- gather: agg[i] = (1+eps)*x[i] + sum_{j in N(i)} x[j] ----------------
// One wave per node (block = 4 nodes). Lane layout: u=lane&15 covers the row as
// 16 x uint4 (16 B each, full 256 B row per group); g=lane>>4 = 4 neighbor groups.
__global__ __launch_bounds__(256) void k_gather(const float* __restrict__ x,
                                                const unsigned short* __restrict__ xb,
                                                const int* __restrict__ srcs,
                                                const int* __restrict__ offsets,
                                                const int* __restrict__ deg,
                                                float* __restrict__ agg) {
    int node = blockIdx.x * 4 + (threadIdx.x >> 6);
    int lane = threadIdx.x & 63;
    int g = lane >> 4;    // neighbor group 0..3
    int u = lane & 15;    // uint4 index within row (row = 16 uint4 = 128 bf16)
    if (node >= N_NODES) return;
    int beg = offsets[node];
    int end = beg + deg[node];
    const uint4* xr = (const uint4*)xb;
    float a0 = 0.f, a1 = 0.f, a2 = 0.f, a3 = 0.f, a4 = 0.f, a5 = 0.f, a6 = 0.f, a7 = 0.f;
    int j = beg + g;
    for (; j + 4 < end; j += 8) {
        int s0 = srcs[j];
        int s1 = srcs[j + 4];
        uint4 A = xr[(size_t)s0 * 16 + u];
        uint4 B = xr[(size_t)s1 * 16 + u];
        a0 += b2f_lo(A.x); a1 += b2f_hi(A.x); a2 += b2f_lo(A.y); a3 += b2f_hi(A.y);
        a4 += b2f_lo(A.z); a5 += b2f_hi(A.z); a6 += b2f_lo(A.w); a7 += b2f_hi(A.w);
        a0 += b2f_lo(B.x); a1 += b2f_hi(B.x); a2 += b2f_lo(B.y); a3 += b2f_hi(B.y);
        a4 += b2f_lo(B.z); a5 += b2f_hi(B.z); a6 += b2f_lo(B.w); a7 += b2f_hi(B.w);
    }
    if (j < end) {
        int s0 = srcs[j];
        uint4 A = xr[(size_t)s0 * 16 + u];
        a0 += b2f_lo(A.x); a1 += b2f_hi(A.x); a2 += b2f_lo(A.y); a3 += b2f_hi(A.y);
        a4 += b2f_lo(A.z); a5 += b2f_hi(A.z); a6 += b2f_lo(A.w); a7 += b2f_hi(A.w);
    }
    // reduce across the 4 neighbor groups (lanes xor 16, 32)
    #pragma unroll
    for (int m = 16; m <= 32; m <<= 1) {
        a0 += __shfl_xor(a0, m, 64); a1 += __shfl_xor(a1, m, 64);
        a2 += __shfl_xor(a2, m, 64); a3 += __shfl_xor(a3, m, 64);
        a4 += __shfl_xor(a4, m, 64); a5 += __shfl_xor(a5, m, 64);
        a6 += __shfl_xor(a6, m, 64); a7 += __shfl_xor(a7, m, 64);
    }
    if (g == 0) {
        const float4* x4 = (const float4*)x;
        float4 xs0 = x4[(size_t)node * 32 + u * 2];
        float4 xs1 = x4[(size_t)node * 32 + u * 2 + 1];
        float4 o0, o1;
        o0.x = fmaf(1.001f, xs0.x, a0); o0.y = fmaf(1.001f, xs0.y, a1);
        o0.z = fmaf(1.001f, xs0.z, a2); o0.w = fmaf(1.001f, xs0.w, a3);
        o1.x = fmaf(1.001f, xs1.x, a4); o1.y = fmaf(1.001f, xs1.y, a5);
        o1.z = fmaf(1.001f, xs1.z, a6); o1.w = fmaf(1.001f, xs1.w, a7);
        float4* ag4 = (float4*)agg;
        ag4[(size_t)node * 32 + u * 2] = o0;
        ag4[(size_t)node * 32 + u * 2 + 1] = o1;
    }
}

// ---------------- bf16 MFMA GEMM: out[M,128] = A[M,128] @ W[128,128] + b ----------------
#define LPAD 136
template <int RELU>
__global__ __launch_bounds__(256, 2) void k_gemm(const float* __restrict__ A,
                                                 const float* __restrict__ Wg,
                                                 const float* __restrict__ bias,
                                                 float* __restrict__ out, int M) {
    __shared__ short Al[128 * LPAD];   // [row][k]
    __shared__ short Wt[128 * LPAD];   // [n][k]  (transposed W)
    __shared__ float bl[128];

    int t = threadIdx.x;
    int row0 = blockIdx.x * 128;

    const float4* A4 = (const float4*)A;
    #pragma unroll
    for (int i = 0; i < 16; ++i) {
        int idx = i * 256 + t;
        int r = idx >> 5;
        int c4 = idx & 31;
        float4 v = make_float4(0.f, 0.f, 0.f, 0.f);
        if (row0 + r < M) v = A4[(size_t)(row0 + r) * 32 + c4];
        ushort4 o;
        o.x = f2b(v.x); o.y = f2b(v.y); o.z = f2b(v.z); o.w = f2b(v.w);
        *(ushort4*)&Al[r * LPAD + c4 * 4] = o;
    }
    const float4* W4 = (const float4*)Wg;
    #pragma unroll
    for (int i = 0; i < 16; ++i) {
        int idx = i * 256 + t;
        int k = idx >> 5;
        int n4 = idx & 31;
        float4 v = W4[k * 32 + n4];
        Wt[(n4 * 4 + 0) * LPAD + k] = (short)f2b(v.x);
        Wt[(n4 * 4 + 1) * LPAD + k] = (short)f2b(v.y);
        Wt[(n4 * 4 + 2) * LPAD + k] = (short)f2b(v.z);
        Wt[(n4 * 4 + 3) * LPAD + k] = (short)f2b(v.w);
    }
    if (t < 32) ((float4*)bl)[t] = ((const float4*)bias)[t];
    __syncthreads();

    int wave = t >> 6;
    int lane = t & 63;
    int quad = lane >> 4;
    int l16 = lane & 15;
    int rowbase = wave * 32;

    float4v acc[2][8];
    #pragma unroll
    for (int mt = 0; mt < 2; ++mt)
        #pragma unroll
        for (int nt = 0; nt < 8; ++nt)
            acc[mt][nt] = (float4v){0.f, 0.f, 0.f, 0.f};

    #pragma unroll
    for (int kc = 0; kc < 4; ++kc) {
        int koff = kc * 32 + quad * 8;
        short8 a0 = *(const short8*)&Al[(rowbase + l16) * LPAD + koff];
        short8 a1 = *(const short8*)&Al[(rowbase + 16 + l16) * LPAD + koff];
        #pragma unroll
        for (int nt = 0; nt < 8; ++nt) {
            short8 bfr = *(const short8*)&Wt[(nt * 16 + l16) * LPAD + koff];
            acc[0][nt] = __builtin_amdgcn_mfma_f32_16x16x32_bf16(a0, bfr, acc[0][nt], 0, 0, 0);
            acc[1][nt] = __builtin_amdgcn_mfma_f32_16x16x32_bf16(a1, bfr, acc[1][nt], 0, 0, 0);
        }
    }

    #pragma unroll
    for (int mt = 0; mt < 2; ++mt) {
        int rloc = rowbase + mt * 16 + quad * 4;
        #pragma unroll
        for (int nt = 0; nt < 8; ++nt) {
            int col = nt * 16 + l16;
            float bv = bl[col];
            #pragma unroll
            for (int r = 0; r < 4; ++r) {
                int grow = row0 + rloc + r;
                if (grow < M) {
                    float v = acc[mt][nt][r] + bv;
                    if (RELU) v = fmaxf(v, 0.f);
                    out[(size_t)grow * 128 + col] = v;
                }
            }
        }
    }
}

extern "C" void kernel_launch(void* const* d_in, const int* in_sizes, int n_in,
                              void* d_out, int out_size, void* d_ws, size_t ws_size,
                              hipStream_t stream) {
    const float* x  = (const float*)d_in[0];
    const int*   ei = (const int*)d_in[1];
    const float* W1 = (const float*)d_in[2];
    const float* b1 = (const float*)d_in[3];
    const float* W2 = (const float*)d_in[4];
    const float* b2 = (const float*)d_in[5];
    float* out = (float*)d_out;

    // workspace layout (bytes):
    //   [0, 12,812,288)          cnt matrix (alias: agg [0,25.6e6) written later by gather)
    //   [25,700,000, 51,300,000) h  (aliases: rank @25.7e6 (6.4MB), srcs @32.1e6 (6.4MB),
    //                                xb @38.5e6 (12.8MB) — all dead before gemm1 writes h)
    //   [51,300,000 ...) deg, offsets, bsum, flag
    char* ws = (char*)d_ws;
    int*            cnt     = (int*)  (ws);
    float*          agg     = (float*)(ws);
    float*          h       = (float*)(ws + 25700000);
    int*            rank    = (int*)  (ws + 25700000);
    int*            srcs    = (int*)  (ws + 32100000);
    unsigned short* xb      = (unsigned short*)(ws + 38500000);
    int*            deg     = (int*)  (ws + 51300000);
    int*            offsets = (int*)  (ws + 51500000);
    int*            bsum    = (int*)  (ws + 51700000);
    int*            flag    = (int*)  (ws + 51710000);

    const int NB_SCAN = (N_NODES + 511) / 512;  // 98

    k_detect<<<1, 256, 0, stream>>>(ei, flag);
    k_cvt<<<(N_NODES * (D / 4) + 255) / 256, 256, 0, stream>>>(x, xb);
    k_zero_cnt<<<1024, 256, 0, stream>>>(cnt);
    k_hist_rank<<<NB_H, 1024, 0, stream>>>(ei, flag, cnt, rank);
    k_colscan<<<NB_SCAN, 512, 0, stream>>>(cnt, deg);
    k_scan1<<<NB_SCAN, 512, 0, stream>>>(deg, offsets, bsum);
    k_scan2<<<1, 128, 0, stream>>>(bsum, NB_SCAN);
    k_scan3<<<NB_SCAN, 512, 0, stream>>>(offsets, bsum);
    k_place<<<NB_H, 1024, 0, stream>>>(ei, flag, offsets, cnt, rank, srcs);
    k_gather<<<(N_NODES + 3) / 4, 256, 0, stream>>>(x, xb, srcs, offsets, deg, agg);

    int gblocks = (N_NODES + 127) / 128;  // 391
    k_gemm<1><<<gblocks, 256, 0, stream>>>(agg, W1, b1, h, N_NODES);
    k_gemm<0><<<gblocks, 256, 0, stream>>>(h, W2, b2, out, N_NODES);
}

// Round 7
// 327.806 us; speedup vs baseline: 1.5401x; 1.1246x over previous
//
#include <hip/hip_runtime.h>
#include <hip/hip_bf16.h>

// GIN layer: out = relu(((1+eps)*x + segment_sum(x[src], dst)) @ W1 + b1) @ W2 + b2
// N=50000 nodes, E=1.6M edges, D=128.

#define N_NODES 50000
#define N_EDGES 1600000
#define D 128

#define NB_H 256                 // private histograms (one owner block each)
#define CHUNK (N_EDGES / NB_H)   // 6250 edges per histogram chunk
#define HROW 50016               // ushorts per hist row; 50016*2 = 100032 B (128-aligned)

#define PL_BLOCKS 1000           // place kernel: contiguous 1600-edge ranges
#define PL_CHUNK 1600

typedef __attribute__((ext_vector_type(8))) short short8;
typedef __attribute__((ext_vector_type(4))) float float4v;

__device__ inline unsigned short f2b(float f) {
    unsigned u = __builtin_bit_cast(unsigned, f);
    u = u + 0x7fffu + ((u >> 16) & 1u);  // RNE
    return (unsigned short)(u >> 16);
}
__device__ inline float b2f_lo(unsigned u) { return __builtin_bit_cast(float, u << 16); }
__device__ inline float b2f_hi(unsigned u) { return __builtin_bit_cast(float, u & 0xffff0000u); }

// ---------------- edge dtype detection ----------------
__global__ void k_detect(const int* __restrict__ ei, int* __restrict__ flag) {
    __shared__ int nz;
    if (threadIdx.x == 0) nz = 0;
    __syncthreads();
    int v = ei[threadIdx.x * 2 + 1];
    if (v != 0) atomicAdd(&nz, 1);
    __syncthreads();
    if (threadIdx.x == 0) *flag = (nz == 0) ? 1 : 0;  // 1 => int64 layout
}

// ---------------- x f32 -> packed bf16 ----------------
__global__ __launch_bounds__(256) void k_cvt(const float* __restrict__ x,
                                             unsigned short* __restrict__ xb) {
    int i = blockIdx.x * blockDim.x + threadIdx.x;
    if (i >= N_NODES * (D / 4)) return;
    float4 v = ((const float4*)x)[i];
    ushort4 o;
    o.x = f2b(v.x); o.y = f2b(v.y); o.z = f2b(v.z); o.w = f2b(v.w);
    ((ushort4*)xb)[i] = o;
}

// ---------------- zero the private-histogram matrix (ushort, as int4) ----------------
__global__ __launch_bounds__(256) void k_zero_cnt(int* __restrict__ cnt) {
    const size_t total4 = (size_t)NB_H * HROW * 2 / 16;  // int4 count
    size_t i = (size_t)blockIdx.x * blockDim.x + threadIdx.x;
    size_t stride = (size_t)gridDim.x * blockDim.x;
    int4 z = make_int4(0, 0, 0, 0);
    for (; i < total4; i += stride) ((int4*)cnt)[i] = z;
}

// ---------------- block-private histogram (packed u16 pairs) + per-edge rank ----
// Block b owns row b; workgroup-scope atomics stay in the XCD's L2.
// Count for dst d lives in 16-bit field (d&1) of word d>>1; max 6250 < 65536.
__global__ __launch_bounds__(1024) void k_hist_rank(const int* __restrict__ ei,
                                                    const int* __restrict__ flag,
                                                    unsigned* __restrict__ cntw,
                                                    int* __restrict__ rank) {
    int b = blockIdx.x;
    int wide = *flag;
    unsigned* hist = cntw + (size_t)b * (HROW / 2);
    int e0 = b * CHUNK;
    for (int i = threadIdx.x; i < CHUNK; i += 1024) {
        int e = e0 + i;
        long long di = (long long)N_EDGES + e;
        int d = wide ? ei[di * 2] : ei[di];
        int r = 0;
        if ((unsigned)d < (unsigned)N_NODES) {
            int sh = (d & 1) * 16;
            unsigned old = __hip_atomic_fetch_add(&hist[d >> 1], 1u << sh,
                                                  __ATOMIC_RELAXED,
                                                  __HIP_MEMORY_SCOPE_WORKGROUP);
            r = (old >> sh) & 0xffffu;
        }
        rank[e] = r;  // coalesced
    }
}

// ---------------- column scan: cnt16[b][d] -> exclusive prefix over b; deg[d]=total ----
__global__ __launch_bounds__(512) void k_colscan(unsigned short* __restrict__ cnt16,
                                                 int* __restrict__ deg) {
    int d = blockIdx.x * 512 + threadIdx.x;
    if (d >= N_NODES) return;
    int run = 0;
    #pragma unroll 8
    for (int b = 0; b < NB_H; ++b) {
        size_t idx = (size_t)b * HROW + d;
        int v = cnt16[idx];
        cnt16[idx] = (unsigned short)run;
        run += v;
    }
    deg[d] = run;
}

// ---------------- multi-block exclusive scan over deg ----------------
__global__ __launch_bounds__(512) void k_scan1(const int* __restrict__ deg,
                                               int* __restrict__ offsets,
                                               int* __restrict__ bsum) {
    __shared__ int tmp[512];
    int t = threadIdx.x;
    int gid = blockIdx.x * 512 + t;
    int v = (gid < N_NODES) ? deg[gid] : 0;
    tmp[t] = v;
    __syncthreads();
    for (int off = 1; off < 512; off <<= 1) {
        int u = (t >= off) ? tmp[t - off] : 0;
        __syncthreads();
        tmp[t] += u;
        __syncthreads();
    }
    if (gid < N_NODES) offsets[gid] = tmp[t] - v;
    if (t == 511) bsum[blockIdx.x] = tmp[511];
}

__global__ __launch_bounds__(128) void k_scan2(int* __restrict__ bsum, int nb) {
    __shared__ int tmp[128];
    int t = threadIdx.x;
    int orig = (t < nb) ? bsum[t] : 0;
    tmp[t] = orig;
    __syncthreads();
    for (int off = 1; off < 128; off <<= 1) {
        int u = (t >= off) ? tmp[t - off] : 0;
        __syncthreads();
        tmp[t] += u;
        __syncthreads();
    }
    if (t < nb) bsum[t] = tmp[t] - orig;
}

__global__ __launch_bounds__(512) void k_scan3(int* __restrict__ offsets,
                                               const int* __restrict__ bsum) {
    int gid = blockIdx.x * 512 + threadIdx.x;
    if (gid < N_NODES) offsets[gid] += bsum[blockIdx.x];
}

// ---------------- CSR place (no atomics, full grid) ----------------
// pos = offsets[d] + cnt16[b][d] + rank[e], b = e / CHUNK (constant-ish per block
// since each block owns a contiguous 1600-edge range -> cnt row stays L2-local).
__global__ __launch_bounds__(512) void k_place(const int* __restrict__ ei,
                                               const int* __restrict__ flag,
                                               const int* __restrict__ offsets,
                                               const unsigned short* __restrict__ cnt16,
                                               const int* __restrict__ rank,
                                               int* __restrict__ srcs) {
    int wide = *flag;
    int e0 = blockIdx.x * PL_CHUNK;
    for (int i = threadIdx.x; i < PL_CHUNK; i += 512) {
        int e = e0 + i;
        if (e >= N_EDGES) return;
        int s = wide ? ei[(long long)e * 2] : ei[e];
        long long di = (long long)N_EDGES + e;
        int d = wide ? ei[di * 2] : ei[di];
        if ((unsigned)d < (unsigned)N_NODES && (unsigned)s < (unsigned)N_NODES) {
            int b = e / CHUNK;
            srcs[offsets[d] + cnt16[(size_t)b * HROW + d] + rank[e]] = s;
        }
    }
}

// ---------------- gather: agg[i] = (1+eps)*x[i] + sum_{j in N(i)} x[j] ----------------
// One wave per node (block = 4 nodes). u=lane&15: row as 16 x uint4; g=lane>>4: 4 groups.
__global__ __launch_bounds__(256) void k_gather(const float* __restrict__ x,
                                                const unsigned short* __restrict__ xb,
                                                const int* __restrict__ srcs,
                                                const int* __restrict__ offsets,
                                                const int* __restrict__ deg,
                                                float* __restrict__ agg) {
    int node = blockIdx.x * 4 + (threadIdx.x >> 6);
    int lane = threadIdx.x & 63;
    int g = lane >> 4;    // neighbor group 0..3
    int u = lane & 15;    // uint4 index within row
    if (node >= N_NODES) return;
    int beg = offsets[node];
    int end = beg + deg[node];
    const uint4* xr = (const uint4*)xb;
    float a0 = 0.f, a1 = 0.f, a2 = 0.f, a3 = 0.f, a4 = 0.f, a5 = 0.f, a6 = 0.f, a7 = 0.f;
    int j = beg + g;
    for (; j + 4 < end; j += 8) {
        int s0 = srcs[j];
        int s1 = srcs[j + 4];
        uint4 A = xr[(size_t)s0 * 16 + u];
        uint4 B = xr[(size_t)s1 * 16 + u];
        a0 += b2f_lo(A.x); a1 += b2f_hi(A.x); a2 += b2f_lo(A.y); a3 += b2f_hi(A.y);
        a4 += b2f_lo(A.z); a5 += b2f_hi(A.z); a6 += b2f_lo(A.w); a7 += b2f_hi(A.w);
        a0 += b2f_lo(B.x); a1 += b2f_hi(B.x); a2 += b2f_lo(B.y); a3 += b2f_hi(B.y);
        a4 += b2f_lo(B.z); a5 += b2f_hi(B.z); a6 += b2f_lo(B.w); a7 += b2f_hi(B.w);
    }
    if (j < end) {
        int s0 = srcs[j];
        uint4 A = xr[(size_t)s0 * 16 + u];
        a0 += b2f_lo(A.x); a1 += b2f_hi(A.x); a2 += b2f_lo(A.y); a3 += b2f_hi(A.y);
        a4 += b2f_lo(A.z); a5 += b2f_hi(A.z); a6 += b2f_lo(A.w); a7 += b2f_hi(A.w);
    }
    #pragma unroll
    for (int m = 16; m <= 32; m <<= 1) {
        a0 += __shfl_xor(a0, m, 64); a1 += __shfl_xor(a1, m, 64);
        a2 += __shfl_xor(a2, m, 64); a3 += __shfl_xor(a3, m, 64);
        a4 += __shfl_xor(a4, m, 64); a5 += __shfl_xor(a5, m, 64);
        a6 += __shfl_xor(a6, m, 64); a7 += __shfl_xor(a7, m, 64);
    }
    if (g == 0) {
        const float4* x4 = (const float4*)x;
        float4 xs0 = x4[(size_t)node * 32 + u * 2];
        float4 xs1 = x4[(size_t)node * 32 + u * 2 + 1];
        float4 o0, o1;
        o0.x = fmaf(1.001f, xs0.x, a0); o0.y = fmaf(1.001f, xs0.y, a1);
        o0.z = fmaf(1.001f, xs0.z, a2); o0.w = fmaf(1.001f, xs0.w, a3);
        o1.x = fmaf(1.001f, xs1.x, a4); o1.y = fmaf(1.001f, xs1.y, a5);
        o1.z = fmaf(1.001f, xs1.z, a6); o1.w = fmaf(1.001f, xs1.w, a7);
        float4* ag4 = (float4*)agg;
        ag4[(size_t)node * 32 + u * 2] = o0;
        ag4[(size_t)node * 32 + u * 2 + 1] = o1;
    }
}

// ---------------- bf16 MFMA GEMM: out[M,128] = A[M,128] @ W[128,128] + b ----------------
#define LPAD 136
template <int RELU>
__global__ __launch_bounds__(256, 2) void k_gemm(const float* __restrict__ A,
                                                 const float* __restrict__ Wg,
                                                 const float* __restrict__ bias,
                                                 float* __restrict__ out, int M) {
    __shared__ short Al[128 * LPAD];   // [row][k]
    __shared__ short Wt[128 * LPAD];   // [n][k]  (transposed W)
    __shared__ float bl[128];

    int t = threadIdx.x;
    int row0 = blockIdx.x * 128;

    const float4* A4 = (const float4*)A;
    #pragma unroll
    for (int i = 0; i < 16; ++i) {
        int idx = i * 256 + t;
        int r = idx >> 5;
        int c4 = idx & 31;
        float4 v = make_float4(0.f, 0.f, 0.f, 0.f);
        if (row0 + r < M) v = A4[(size_t)(row0 + r) * 32 + c4];
        ushort4 o;
        o.x = f2b(v.x); o.y = f2b(v.y); o.z = f2b(v.z); o.w = f2b(v.w);
        *(ushort4*)&Al[r * LPAD + c4 * 4] = o;
    }
    const float4* W4 = (const float4*)Wg;
    #pragma unroll
    for (int i = 0; i < 16; ++i) {
        int idx = i * 256 + t;
        int k = idx >> 5;
        int n4 = idx & 31;
        float4 v = W4[k * 32 + n4];
        Wt[(n4 * 4 + 0) * LPAD + k] = (short)f2b(v.x);
        Wt[(n4 * 4 + 1) * LPAD + k] = (short)f2b(v.y);
        Wt[(n4 * 4 + 2) * LPAD + k] = (short)f2b(v.z);
        Wt[(n4 * 4 + 3) * LPAD + k] = (short)f2b(v.w);
    }
    if (t < 32) ((float4*)bl)[t] = ((const float4*)bias)[t];
    __syncthreads();

    int wave = t >> 6;
    int lane = t & 63;
    int quad = lane >> 4;
    int l16 = lane & 15;
    int rowbase = wave * 32;

    float4v acc[2][8];
    #pragma unroll
    for (int mt = 0; mt < 2; ++mt)
        #pragma unroll
        for (int nt = 0; nt < 8; ++nt)
            acc[mt][nt] = (float4v){0.f, 0.f, 0.f, 0.f};

    #pragma unroll
    for (int kc = 0; kc < 4; ++kc) {
        int koff = kc * 32 + quad * 8;
        short8 a0 = *(const short8*)&Al[(rowbase + l16) * LPAD + koff];
        short8 a1 = *(const short8*)&Al[(rowbase + 16 + l16) * LPAD + koff];
        #pragma unroll
        for (int nt = 0; nt < 8; ++nt) {
            short8 bfr = *(const short8*)&Wt[(nt * 16 + l16) * LPAD + koff];
            acc[0][nt] = __builtin_amdgcn_mfma_f32_16x16x32_bf16(a0, bfr, acc[0][nt], 0, 0, 0);
            acc[1][nt] = __builtin_amdgcn_mfma_f32_16x16x32_bf16(a1, bfr, acc[1][nt], 0, 0, 0);
        }
    }

    #pragma unroll
    for (int mt = 0; mt < 2; ++mt) {
        int rloc = rowbase + mt * 16 + quad * 4;
        #pragma unroll
        for (int nt = 0; nt < 8; ++nt) {
            int col = nt * 16 + l16;
            float bv = bl[col];
            #pragma unroll
            for (int r = 0; r < 4; ++r) {
                int grow = row0 + rloc + r;
                if (grow < M) {
                    float v = acc[mt][nt][r] + bv;
                    if (RELU) v = fmaxf(v, 0.f);
                    out[(size_t)grow * 128 + col] = v;
                }
            }
        }
    }
}

extern "C" void kernel_launch(void* const* d_in, const int* in_sizes, int n_in,
                              void* d_out, int out_size, void* d_ws, size_t ws_size,
                              hipStream_t stream) {
    const float* x  = (const float*)d_in[0];
    const int*   ei = (const int*)d_in[1];
    const float* W1 = (const float*)d_in[2];
    const float* b1 = (const float*)d_in[3];
    const float* W2 = (const float*)d_in[4];
    const float* b2 = (const float*)d_in[5];
    float* out = (float*)d_out;

    // workspace layout (bytes):
    //   [0, 25,608,192)          cnt matrix u16 (alias: agg [0,25.6e6) written by gather)
    //   [25,700,000, 51,300,000) h  (aliases: rank @25.7e6 (6.4MB), srcs @32.1e6 (6.4MB),
    //                                xb @38.5e6 (12.8MB) — all dead before gemm1 writes h)
    //   [51,300,000 ...) deg, offsets, bsum, flag
    char* ws = (char*)d_ws;
    unsigned*       cntw    = (unsigned*)(ws);
    unsigned short* cnt16   = (unsigned short*)(ws);
    float*          agg     = (float*)(ws);
    float*          h       = (float*)(ws + 25700000);
    int*            rank    = (int*)  (ws + 25700000);
    int*            srcs    = (int*)  (ws + 32100000);
    unsigned short* xb      = (unsigned short*)(ws + 38500000);
    int*            deg     = (int*)  (ws + 51300000);
    int*            offsets = (int*)  (ws + 51500000);
    int*            bsum    = (int*)  (ws + 51700000);
    int*            flag    = (int*)  (ws + 51710000);

    const int NB_SCAN = (N_NODES + 511) / 512;  // 98

    k_detect<<<1, 256, 0, stream>>>(ei, flag);
    k_cvt<<<(N_NODES * (D / 4) + 255) / 256, 256, 0, stream>>>(x, xb);
    k_zero_cnt<<<1024, 256, 0, stream>>>((int*)cntw);
    k_hist_rank<<<NB_H, 1024, 0, stream>>>(ei, flag, cntw, rank);
    k_colscan<<<NB_SCAN, 512, 0, stream>>>(cnt16, deg);
    k_scan1<<<NB_SCAN, 512, 0, stream>>>(deg, offsets, bsum);
    k_scan2<<<1, 128, 0, stream>>>(bsum, NB_SCAN);
    k_scan3<<<NB_SCAN, 512, 0, stream>>>(offsets, bsum);
    k_place<<<PL_BLOCKS, 512, 0, stream>>>(ei, flag, offsets, cnt16, rank, srcs);
    k_gather<<<(N_NODES + 3) / 4, 256, 0, stream>>>(x, xb, srcs, offsets, deg, agg);

    int gblocks = (N_NODES + 127) / 128;  // 391
    k_gemm<1><<<gblocks, 256, 0, stream>>>(agg, W1, b1, h, N_NODES);
    k_gemm<0><<<gblocks, 256, 0, stream>>>(h, W2, b2, out, N_NODES);
}

// Round 8
// 264.327 us; speedup vs baseline: 1.9100x; 1.2402x over previous
//
#include <hip/hip_runtime.h>
#include <hip/hip_bf16.h>

// GIN layer: out = relu(((1+eps)*x + segment_sum(x[src], dst)) @ W1 + b1) @ W2 + b2
// N=50000 nodes, E=1.6M edges, D=128.

#define N_NODES 50000
#define N_EDGES 1600000
#define D 128

#define NB_H 256                 // private histograms (one owner block each)
#define CHUNK (N_EDGES / NB_H)   // 6250 edges per chunk; rank max 6249 < 65536
#define HROW 50016               // ushorts per hist row (100,032 B, 128-aligned)

#define PL_BLOCKS 1000           // place kernel: contiguous 1600-edge ranges
#define PL_CHUNK 1600

typedef __attribute__((ext_vector_type(8))) short short8;
typedef __attribute__((ext_vector_type(4))) float float4v;

__device__ inline unsigned short f2b(float f) {
    unsigned u = __builtin_bit_cast(unsigned, f);
    u = u + 0x7fffu + ((u >> 16) & 1u);  // RNE
    return (unsigned short)(u >> 16);
}
__device__ inline float b2f_lo(unsigned u) { return __builtin_bit_cast(float, u << 16); }
__device__ inline float b2f_hi(unsigned u) { return __builtin_bit_cast(float, u & 0xffff0000u); }

// ---------------- edge dtype detection ----------------
__global__ void k_detect(const int* __restrict__ ei, int* __restrict__ flag) {
    __shared__ int nz;
    if (threadIdx.x == 0) nz = 0;
    __syncthreads();
    int v = ei[threadIdx.x * 2 + 1];
    if (v != 0) atomicAdd(&nz, 1);
    __syncthreads();
    if (threadIdx.x == 0) *flag = (nz == 0) ? 1 : 0;  // 1 => int64 layout
}

// ---------------- x f32 -> packed bf16 ----------------
__global__ __launch_bounds__(256) void k_cvt(const float* __restrict__ x,
                                             unsigned short* __restrict__ xb) {
    int i = blockIdx.x * blockDim.x + threadIdx.x;
    if (i >= N_NODES * (D / 4)) return;
    float4 v = ((const float4*)x)[i];
    ushort4 o;
    o.x = f2b(v.x); o.y = f2b(v.y); o.z = f2b(v.z); o.w = f2b(v.w);
    ((ushort4*)xb)[i] = o;
}

// ---------------- LDS histogram (packed u16 pairs) + per-edge rank ----------------
// Each block builds its 100 KB hist in LDS (fast LDS atomics), then streams the
// row to global coalesced. No global pre-zero needed.
__global__ __launch_bounds__(1024) void k_hist_rank(const int* __restrict__ ei,
                                                    const int* __restrict__ flag,
                                                    unsigned* __restrict__ cntw,
                                                    int* __restrict__ rank) {
    __shared__ unsigned hist[HROW / 2];  // 25008 u32 = 100,032 B
    int b = blockIdx.x;
    for (int i = threadIdx.x; i < HROW / 2; i += 1024) hist[i] = 0u;
    __syncthreads();
    int wide = *flag;
    int e0 = b * CHUNK;
    for (int i = threadIdx.x; i < CHUNK; i += 1024) {
        int e = e0 + i;
        long long di = (long long)N_EDGES + e;
        int d = wide ? ei[di * 2] : ei[di];
        int r = 0;
        if ((unsigned)d < (unsigned)N_NODES) {
            int sh = (d & 1) * 16;
            unsigned old = atomicAdd(&hist[d >> 1], 1u << sh);
            r = (old >> sh) & 0xffffu;
        }
        rank[e] = r;  // coalesced
    }
    __syncthreads();
    unsigned* row = cntw + (size_t)b * (HROW / 2);
    for (int i = threadIdx.x; i < HROW / 2; i += 1024) row[i] = hist[i];
}

// ---------------- column scan: cnt16[b][d] -> exclusive prefix over b; deg[d]=total ----
__global__ __launch_bounds__(512) void k_colscan(unsigned short* __restrict__ cnt16,
                                                 int* __restrict__ deg) {
    int d = blockIdx.x * 512 + threadIdx.x;
    if (d >= N_NODES) return;
    int run = 0;
    #pragma unroll 8
    for (int b = 0; b < NB_H; ++b) {
        size_t idx = (size_t)b * HROW + d;
        int v = cnt16[idx];
        cnt16[idx] = (unsigned short)run;
        run += v;
    }
    deg[d] = run;
}

// ---------------- multi-block exclusive scan over deg ----------------
__global__ __launch_bounds__(512) void k_scan1(const int* __restrict__ deg,
                                               int* __restrict__ offsets,
                                               int* __restrict__ bsum) {
    __shared__ int tmp[512];
    int t = threadIdx.x;
    int gid = blockIdx.x * 512 + t;
    int v = (gid < N_NODES) ? deg[gid] : 0;
    tmp[t] = v;
    __syncthreads();
    for (int off = 1; off < 512; off <<= 1) {
        int u = (t >= off) ? tmp[t - off] : 0;
        __syncthreads();
        tmp[t] += u;
        __syncthreads();
    }
    if (gid < N_NODES) offsets[gid] = tmp[t] - v;
    if (t == 511) bsum[blockIdx.x] = tmp[511];
}

__global__ __launch_bounds__(128) void k_scan2(int* __restrict__ bsum, int nb) {
    __shared__ int tmp[128];
    int t = threadIdx.x;
    int orig = (t < nb) ? bsum[t] : 0;
    tmp[t] = orig;
    __syncthreads();
    for (int off = 1; off < 128; off <<= 1) {
        int u = (t >= off) ? tmp[t - off] : 0;
        __syncthreads();
        tmp[t] += u;
        __syncthreads();
    }
    if (t < nb) bsum[t] = tmp[t] - orig;
}

__global__ __launch_bounds__(512) void k_scan3(int* __restrict__ offsets,
                                               const int* __restrict__ bsum) {
    int gid = blockIdx.x * 512 + threadIdx.x;
    if (gid < N_NODES) offsets[gid] += bsum[blockIdx.x];
}

// ---------------- CSR place (no atomics, full grid) ----------------
__global__ __launch_bounds__(512) void k_place(const int* __restrict__ ei,
                                               const int* __restrict__ flag,
                                               const int* __restrict__ offsets,
                                               const unsigned short* __restrict__ cnt16,
                                               const int* __restrict__ rank,
                                               int* __restrict__ srcs) {
    int wide = *flag;
    int e0 = blockIdx.x * PL_CHUNK;
    for (int i = threadIdx.x; i < PL_CHUNK; i += 512) {
        int e = e0 + i;
        if (e >= N_EDGES) return;
        int s = wide ? ei[(long long)e * 2] : ei[e];
        long long di = (long long)N_EDGES + e;
        int d = wide ? ei[di * 2] : ei[di];
        if ((unsigned)d < (unsigned)N_NODES && (unsigned)s < (unsigned)N_NODES) {
            int b = e / CHUNK;
            srcs[offsets[d] + cnt16[(size_t)b * HROW + d] + rank[e]] = s;
        }
    }
}

// ---------------- gather: aggb[i] = bf16((1+eps)*x[i] + sum_{j in N(i)} x[j]) ----------
// One wave per node (block = 4 nodes). u=lane&15: row as 16 x uint4; g=lane>>4: 4 groups.
// Unroll x4 for memory-level parallelism.
__global__ __launch_bounds__(256) void k_gather(const float* __restrict__ x,
                                                const unsigned short* __restrict__ xb,
                                                const int* __restrict__ srcs,
                                                const int* __restrict__ offsets,
                                                const int* __restrict__ deg,
                                                unsigned short* __restrict__ aggb) {
    int node = blockIdx.x * 4 + (threadIdx.x >> 6);
    int lane = threadIdx.x & 63;
    int g = lane >> 4;    // neighbor group 0..3
    int u = lane & 15;    // uint4 index within row
    if (node >= N_NODES) return;
    int beg = offsets[node];
    int end = beg + deg[node];
    const uint4* xr = (const uint4*)xb;
    float a0 = 0.f, a1 = 0.f, a2 = 0.f, a3 = 0.f, a4 = 0.f, a5 = 0.f, a6 = 0.f, a7 = 0.f;
    int j = beg + g;
    for (; j + 12 < end; j += 16) {
        int s0 = srcs[j];
        int s1 = srcs[j + 4];
        int s2 = srcs[j + 8];
        int s3 = srcs[j + 12];
        uint4 A = xr[(size_t)s0 * 16 + u];
        uint4 B = xr[(size_t)s1 * 16 + u];
        uint4 C = xr[(size_t)s2 * 16 + u];
        uint4 E = xr[(size_t)s3 * 16 + u];
        a0 += b2f_lo(A.x); a1 += b2f_hi(A.x); a2 += b2f_lo(A.y); a3 += b2f_hi(A.y);
        a4 += b2f_lo(A.z); a5 += b2f_hi(A.z); a6 += b2f_lo(A.w); a7 += b2f_hi(A.w);
        a0 += b2f_lo(B.x); a1 += b2f_hi(B.x); a2 += b2f_lo(B.y); a3 += b2f_hi(B.y);
        a4 += b2f_lo(B.z); a5 += b2f_hi(B.z); a6 += b2f_lo(B.w); a7 += b2f_hi(B.w);
        a0 += b2f_lo(C.x); a1 += b2f_hi(C.x); a2 += b2f_lo(C.y); a3 += b2f_hi(C.y);
        a4 += b2f_lo(C.z); a5 += b2f_hi(C.z); a6 += b2f_lo(C.w); a7 += b2f_hi(C.w);
        a0 += b2f_lo(E.x); a1 += b2f_hi(E.x); a2 += b2f_lo(E.y); a3 += b2f_hi(E.y);
        a4 += b2f_lo(E.z); a5 += b2f_hi(E.z); a6 += b2f_lo(E.w); a7 += b2f_hi(E.w);
    }
    for (; j < end; j += 4) {
        int s0 = srcs[j];
        uint4 A = xr[(size_t)s0 * 16 + u];
        a0 += b2f_lo(A.x); a1 += b2f_hi(A.x); a2 += b2f_lo(A.y); a3 += b2f_hi(A.y);
        a4 += b2f_lo(A.z); a5 += b2f_hi(A.z); a6 += b2f_lo(A.w); a7 += b2f_hi(A.w);
    }
    #pragma unroll
    for (int m = 16; m <= 32; m <<= 1) {
        a0 += __shfl_xor(a0, m, 64); a1 += __shfl_xor(a1, m, 64);
        a2 += __shfl_xor(a2, m, 64); a3 += __shfl_xor(a3, m, 64);
        a4 += __shfl_xor(a4, m, 64); a5 += __shfl_xor(a5, m, 64);
        a6 += __shfl_xor(a6, m, 64); a7 += __shfl_xor(a7, m, 64);
    }
    if (g == 0) {
        const float4* x4 = (const float4*)x;
        float4 xs0 = x4[(size_t)node * 32 + u * 2];
        float4 xs1 = x4[(size_t)node * 32 + u * 2 + 1];
        float f0 = fmaf(1.001f, xs0.x, a0), f1 = fmaf(1.001f, xs0.y, a1);
        float f2 = fmaf(1.001f, xs0.z, a2), f3 = fmaf(1.001f, xs0.w, a3);
        float f4 = fmaf(1.001f, xs1.x, a4), f5 = fmaf(1.001f, xs1.y, a5);
        float f6 = fmaf(1.001f, xs1.z, a6), f7 = fmaf(1.001f, xs1.w, a7);
        uint4 o;
        o.x = (unsigned)f2b(f0) | ((unsigned)f2b(f1) << 16);
        o.y = (unsigned)f2b(f2) | ((unsigned)f2b(f3) << 16);
        o.z = (unsigned)f2b(f4) | ((unsigned)f2b(f5) << 16);
        o.w = (unsigned)f2b(f6) | ((unsigned)f2b(f7) << 16);
        ((uint4*)aggb)[(size_t)node * 16 + u] = o;
    }
}

// ---------------- bf16 MFMA GEMM: out[M,128] = A_bf16[M,128] @ W[128,128] + b ----------
// A is already bf16 (ushort). Output f32 or bf16 per template.
#define LPAD 136
template <int RELU, int OUT_BF16>
__global__ __launch_bounds__(256, 2) void k_gemm(const unsigned short* __restrict__ A,
                                                 const float* __restrict__ Wg,
                                                 const float* __restrict__ bias,
                                                 void* __restrict__ outv, int M) {
    __shared__ short Al[128 * LPAD];   // [row][k]
    __shared__ short Wt[128 * LPAD];   // [n][k]  (transposed W)
    __shared__ float bl[128];

    int t = threadIdx.x;
    int row0 = blockIdx.x * 128;

    // stage A: pure uint4 copies (row = 16 uint4 = 128 bf16)
    const uint4* A16 = (const uint4*)A;
    #pragma unroll
    for (int i = 0; i < 8; ++i) {
        int idx = i * 256 + t;      // 0..2047
        int r = idx >> 4;           // 0..127
        int c = idx & 15;           // uint4 within row
        uint4 v = make_uint4(0u, 0u, 0u, 0u);
        if (row0 + r < M) v = A16[(size_t)(row0 + r) * 16 + c];
        *(uint4*)&Al[r * LPAD + c * 8] = v;
    }
    // stage W transposed (f32 -> bf16)
    const float4* W4 = (const float4*)Wg;
    #pragma unroll
    for (int i = 0; i < 16; ++i) {
        int idx = i * 256 + t;
        int k = idx >> 5;
        int n4 = idx & 31;
        float4 v = W4[k * 32 + n4];
        Wt[(n4 * 4 + 0) * LPAD + k] = (short)f2b(v.x);
        Wt[(n4 * 4 + 1) * LPAD + k] = (short)f2b(v.y);
        Wt[(n4 * 4 + 2) * LPAD + k] = (short)f2b(v.z);
        Wt[(n4 * 4 + 3) * LPAD + k] = (short)f2b(v.w);
    }
    if (t < 32) ((float4*)bl)[t] = ((const float4*)bias)[t];
    __syncthreads();

    int wave = t >> 6;
    int lane = t & 63;
    int quad = lane >> 4;
    int l16 = lane & 15;
    int rowbase = wave * 32;

    float4v acc[2][8];
    #pragma unroll
    for (int mt = 0; mt < 2; ++mt)
        #pragma unroll
        for (int nt = 0; nt < 8; ++nt)
            acc[mt][nt] = (float4v){0.f, 0.f, 0.f, 0.f};

    #pragma unroll
    for (int kc = 0; kc < 4; ++kc) {
        int koff = kc * 32 + quad * 8;
        short8 a0 = *(const short8*)&Al[(rowbase + l16) * LPAD + koff];
        short8 a1 = *(const short8*)&Al[(rowbase + 16 + l16) * LPAD + koff];
        #pragma unroll
        for (int nt = 0; nt < 8; ++nt) {
            short8 bfr = *(const short8*)&Wt[(nt * 16 + l16) * LPAD + koff];
            acc[0][nt] = __builtin_amdgcn_mfma_f32_16x16x32_bf16(a0, bfr, acc[0][nt], 0, 0, 0);
            acc[1][nt] = __builtin_amdgcn_mfma_f32_16x16x32_bf16(a1, bfr, acc[1][nt], 0, 0, 0);
        }
    }

    #pragma unroll
    for (int mt = 0; mt < 2; ++mt) {
        int rloc = rowbase + mt * 16 + quad * 4;
        #pragma unroll
        for (int nt = 0; nt < 8; ++nt) {
            int col = nt * 16 + l16;
            float bv = bl[col];
            #pragma unroll
            for (int r = 0; r < 4; ++r) {
                int grow = row0 + rloc + r;
                if (grow < M) {
                    float v = acc[mt][nt][r] + bv;
                    if (RELU) v = fmaxf(v, 0.f);
                    if (OUT_BF16)
                        ((unsigned short*)outv)[(size_t)grow * 128 + col] = f2b(v);
                    else
                        ((float*)outv)[(size_t)grow * 128 + col] = v;
                }
            }
        }
    }
}

extern "C" void kernel_launch(void* const* d_in, const int* in_sizes, int n_in,
                              void* d_out, int out_size, void* d_ws, size_t ws_size,
                              hipStream_t stream) {
    const float* x  = (const float*)d_in[0];
    const int*   ei = (const int*)d_in[1];
    const float* W1 = (const float*)d_in[2];
    const float* b1 = (const float*)d_in[3];
    const float* W2 = (const float*)d_in[4];
    const float* b2 = (const float*)d_in[5];
    float* out = (float*)d_out;

    // workspace layout (bytes):
    //   [0, 25,608,192)        cnt u16 matrix — dead after place
    //   [0, 12,800,000)        aggb (bf16) — alias over cnt, written by gather
    //   [25,700,000, 38,500,000) h bf16 — aliases rank @25.7e6 (6.4MB) and
    //                              srcs @32.1e6 (6.4MB), both dead before gemm1
    //   [38,500,000, 51,300,000) xb (bf16 x) — dead after gather
    //   [51,300,000 ...) deg, offsets, bsum, flag
    char* ws = (char*)d_ws;
    unsigned*       cntw    = (unsigned*)(ws);
    unsigned short* cnt16   = (unsigned short*)(ws);
    unsigned short* aggb    = (unsigned short*)(ws);
    unsigned short* hb      = (unsigned short*)(ws + 25700000);
    int*            rank    = (int*)  (ws + 25700000);
    int*            srcs    = (int*)  (ws + 32100000);
    unsigned short* xb      = (unsigned short*)(ws + 38500000);
    int*            deg     = (int*)  (ws + 51300000);
    int*            offsets = (int*)  (ws + 51500000);
    int*            bsum    = (int*)  (ws + 51700000);
    int*            flag    = (int*)  (ws + 51710000);

    const int NB_SCAN = (N_NODES + 511) / 512;  // 98

    k_detect<<<1, 256, 0, stream>>>(ei, flag);
    k_cvt<<<(N_NODES * (D / 4) + 255) / 256, 256, 0, stream>>>(x, xb);
    k_hist_rank<<<NB_H, 1024, 0, stream>>>(ei, flag, cntw, rank);
    k_colscan<<<NB_SCAN, 512, 0, stream>>>(cnt16, deg);
    k_scan1<<<NB_SCAN, 512, 0, stream>>>(deg, offsets, bsum);
    k_scan2<<<1, 128, 0, stream>>>(bsum, NB_SCAN);
    k_scan3<<<NB_SCAN, 512, 0, stream>>>(offsets, bsum);
    k_place<<<PL_BLOCKS, 512, 0, stream>>>(ei, flag, offsets, cnt16, rank, srcs);
    k_gather<<<(N_NODES + 3) / 4, 256, 0, stream>>>(x, xb, srcs, offsets, deg, aggb);

    int gblocks = (N_NODES + 127) / 128;  // 391
    k_gemm<1, 1><<<gblocks, 256, 0, stream>>>(aggb, W1, b1, hb, N_NODES);
    k_gemm<0, 0><<<gblocks, 256, 0, stream>>>(hb, W2, b2, out, N_NODES);
}

// Round 9
// 258.988 us; speedup vs baseline: 1.9494x; 1.0206x over previous
//
#include <hip/hip_runtime.h>
#include <hip/hip_bf16.h>

// GIN layer: out = relu(((1+eps)*x + segment_sum(x[src], dst)) @ W1 + b1) @ W2 + b2
// N=50000 nodes, E=1.6M edges, D=128.

#define N_NODES 50000
#define N_EDGES 1600000
#define D 128

#define NB_H 256                 // private histograms (one owner block each)
#define CHUNK (N_EDGES / NB_H)   // 6250 edges per chunk; rank max 6249 < 65536
#define HROW 50016               // ushorts per hist row (100,032 B, 128-aligned)

typedef __attribute__((ext_vector_type(8))) short short8;
typedef __attribute__((ext_vector_type(4))) float float4v;

__device__ inline unsigned short f2b(float f) {
    unsigned u = __builtin_bit_cast(unsigned, f);
    u = u + 0x7fffu + ((u >> 16) & 1u);  // RNE
    return (unsigned short)(u >> 16);
}
__device__ inline float b2f_lo(unsigned u) { return __builtin_bit_cast(float, u << 16); }
__device__ inline float b2f_hi(unsigned u) { return __builtin_bit_cast(float, u & 0xffff0000u); }

// ---------------- x f32 -> packed bf16, with edge-dtype detect in block 0 --------------
// int64 edge_index => every odd int32 word of ei is 0 (ids < 50000).
__global__ __launch_bounds__(256) void k_cvt(const float* __restrict__ x,
                                             unsigned short* __restrict__ xb,
                                             const int* __restrict__ ei,
                                             int* __restrict__ flag) {
    if (blockIdx.x == 0) {
        __shared__ int nz;
        if (threadIdx.x == 0) nz = 0;
        __syncthreads();
        if (ei[threadIdx.x * 2 + 1] != 0) atomicAdd(&nz, 1);
        __syncthreads();
        if (threadIdx.x == 0) *flag = (nz == 0) ? 1 : 0;  // 1 => int64 layout
    }
    int i = blockIdx.x * blockDim.x + threadIdx.x;
    if (i >= N_NODES * (D / 4)) return;
    float4 v = ((const float4*)x)[i];
    ushort4 o;
    o.x = f2b(v.x); o.y = f2b(v.y); o.z = f2b(v.z); o.w = f2b(v.w);
    ((ushort4*)xb)[i] = o;
}

// ---------------- LDS histogram (packed u16 pairs) + per-edge rank ----------------
__global__ __launch_bounds__(1024) void k_hist_rank(const int* __restrict__ ei,
                                                    const int* __restrict__ flag,
                                                    unsigned* __restrict__ cntw,
                                                    int* __restrict__ rank) {
    __shared__ unsigned hist[HROW / 2];  // 25008 u32 = 100,032 B
    int b = blockIdx.x;
    for (int i = threadIdx.x; i < HROW / 2; i += 1024) hist[i] = 0u;
    __syncthreads();
    int wide = *flag;
    int e0 = b * CHUNK;
    for (int i = threadIdx.x; i < CHUNK; i += 1024) {
        int e = e0 + i;
        long long di = (long long)N_EDGES + e;
        int d = wide ? ei[di * 2] : ei[di];
        int r = 0;
        if ((unsigned)d < (unsigned)N_NODES) {
            int sh = (d & 1) * 16;
            unsigned old = atomicAdd(&hist[d >> 1], 1u << sh);
            r = (old >> sh) & 0xffffu;
        }
        rank[e] = r;  // coalesced
    }
    __syncthreads();
    unsigned* row = cntw + (size_t)b * (HROW / 2);
    for (int i = threadIdx.x; i < HROW / 2; i += 1024) row[i] = hist[i];
}

// ---------------- fused column scan + per-block scan of deg ----------------
// cnt16[b][d] -> exclusive prefix over b; deg[d] = total; offsets[d] = within-block
// exclusive prefix of deg; bsum[block] = block total.
__global__ __launch_bounds__(512) void k_colscan_scan1(unsigned short* __restrict__ cnt16,
                                                       int* __restrict__ deg,
                                                       int* __restrict__ offsets,
                                                       int* __restrict__ bsum) {
    __shared__ int tmp[512];
    int t = threadIdx.x;
    int d = blockIdx.x * 512 + t;
    int run = 0;
    if (d < N_NODES) {
        #pragma unroll 8
        for (int b = 0; b < NB_H; ++b) {
            size_t idx = (size_t)b * HROW + d;
            int v = cnt16[idx];
            cnt16[idx] = (unsigned short)run;
            run += v;
        }
        deg[d] = run;
    }
    tmp[t] = run;
    __syncthreads();
    for (int off = 1; off < 512; off <<= 1) {
        int u = (t >= off) ? tmp[t - off] : 0;
        __syncthreads();
        tmp[t] += u;
        __syncthreads();
    }
    if (d < N_NODES) offsets[d] = tmp[t] - run;
    if (t == 511) bsum[blockIdx.x] = tmp[511];
}

// ---------------- fused scan of block sums + add base ----------------
// Every block redundantly scans the 98 partials in LDS, then adds its base.
__global__ __launch_bounds__(512) void k_scan23(int* __restrict__ offsets,
                                                const int* __restrict__ bsum, int nb) {
    __shared__ int tmp[128];
    int t = threadIdx.x;
    if (t < 128) tmp[t] = (t < nb) ? bsum[t] : 0;
    __syncthreads();
    for (int off = 1; off < 128; off <<= 1) {
        int v = (t >= off && t < 128) ? tmp[t - off] : 0;
        __syncthreads();
        if (t < 128) tmp[t] += v;
        __syncthreads();
    }
    int base = (blockIdx.x == 0) ? 0 : tmp[blockIdx.x - 1];
    int gid = blockIdx.x * 512 + t;
    if (gid < N_NODES) offsets[gid] += base;
}

// ---------------- CSR place (no atomics, one edge per thread) ----------------
__global__ __launch_bounds__(1024) void k_place(const int* __restrict__ ei,
                                                const int* __restrict__ flag,
                                                const int* __restrict__ offsets,
                                                const unsigned short* __restrict__ cnt16,
                                                const int* __restrict__ rank,
                                                int* __restrict__ srcs) {
    int e = blockIdx.x * 1024 + threadIdx.x;
    if (e >= N_EDGES) return;
    int wide = *flag;
    int s = wide ? ei[(long long)e * 2] : ei[e];
    long long di = (long long)N_EDGES + e;
    int d = wide ? ei[di * 2] : ei[di];
    if ((unsigned)d < (unsigned)N_NODES && (unsigned)s < (unsigned)N_NODES) {
        int b = e / CHUNK;
        srcs[offsets[d] + cnt16[(size_t)b * HROW + d] + rank[e]] = s;
    }
}

// ---------------- gather: aggb[i] = bf16((1+eps)*x[i] + sum_{j in N(i)} x[j]) ----------
// One wave per node (block = 4 nodes). Row = 32 lanes x uint2 (256 B); 2 neighbor
// groups x unroll 8 = 16 outstanding row loads per wave (MLP >> latency-BW product).
__global__ __launch_bounds__(256) void k_gather(const float* __restrict__ x,
                                                const unsigned short* __restrict__ xb,
                                                const int* __restrict__ srcs,
                                                const int* __restrict__ offsets,
                                                const int* __restrict__ deg,
                                                unsigned short* __restrict__ aggb) {
    int node = blockIdx.x * 4 + (threadIdx.x >> 6);
    int lane = threadIdx.x & 63;
    int g = lane >> 5;    // neighbor group 0..1
    int u = lane & 31;    // uint2 index within row (32 x 8 B = 256 B)
    if (node >= N_NODES) return;
    int beg = offsets[node];
    int end = beg + deg[node];
    const uint2* xr = (const uint2*)xb;
    float a0 = 0.f, a1 = 0.f, a2 = 0.f, a3 = 0.f;
    int j = beg + g;
    for (; j + 14 < end; j += 16) {
        int ss[8];
        #pragma unroll
        for (int q = 0; q < 8; ++q) ss[q] = srcs[j + 2 * q];
        #pragma unroll
        for (int q = 0; q < 8; ++q) {
            uint2 A = xr[(size_t)ss[q] * 32 + u];
            a0 += b2f_lo(A.x); a1 += b2f_hi(A.x);
            a2 += b2f_lo(A.y); a3 += b2f_hi(A.y);
        }
    }
    for (; j < end; j += 2) {
        uint2 A = xr[(size_t)srcs[j] * 32 + u];
        a0 += b2f_lo(A.x); a1 += b2f_hi(A.x);
        a2 += b2f_lo(A.y); a3 += b2f_hi(A.y);
    }
    a0 += __shfl_xor(a0, 32, 64); a1 += __shfl_xor(a1, 32, 64);
    a2 += __shfl_xor(a2, 32, 64); a3 += __shfl_xor(a3, 32, 64);
    if (g == 0) {
        // cols 4u .. 4u+3
        float4 xs = ((const float4*)x)[(size_t)node * 32 + u];
        float f0 = fmaf(1.001f, xs.x, a0), f1 = fmaf(1.001f, xs.y, a1);
        float f2 = fmaf(1.001f, xs.z, a2), f3 = fmaf(1.001f, xs.w, a3);
        uint2 o;
        o.x = (unsigned)f2b(f0) | ((unsigned)f2b(f1) << 16);
        o.y = (unsigned)f2b(f2) | ((unsigned)f2b(f3) << 16);
        ((uint2*)aggb)[(size_t)node * 32 + u] = o;
    }
}

// ---------------- bf16 MFMA GEMM: out[M,128] = A_bf16[M,128] @ W[128,128] + b ----------
#define LPAD 136
template <int RELU, int OUT_BF16>
__global__ __launch_bounds__(256, 2) void k_gemm(const unsigned short* __restrict__ A,
                                                 const float* __restrict__ Wg,
                                                 const float* __restrict__ bias,
                                                 void* __restrict__ outv, int M) {
    __shared__ short Al[128 * LPAD];   // [row][k]
    __shared__ short Wt[128 * LPAD];   // [n][k]  (transposed W)
    __shared__ float bl[128];

    int t = threadIdx.x;
    int row0 = blockIdx.x * 128;

    const uint4* A16 = (const uint4*)A;
    #pragma unroll
    for (int i = 0; i < 8; ++i) {
        int idx = i * 256 + t;      // 0..2047
        int r = idx >> 4;           // 0..127
        int c = idx & 15;           // uint4 within row
        uint4 v = make_uint4(0u, 0u, 0u, 0u);
        if (row0 + r < M) v = A16[(size_t)(row0 + r) * 16 + c];
        *(uint4*)&Al[r * LPAD + c * 8] = v;
    }
    const float4* W4 = (const float4*)Wg;
    #pragma unroll
    for (int i = 0; i < 16; ++i) {
        int idx = i * 256 + t;
        int k = idx >> 5;
        int n4 = idx & 31;
        float4 v = W4[k * 32 + n4];
        Wt[(n4 * 4 + 0) * LPAD + k] = (short)f2b(v.x);
        Wt[(n4 * 4 + 1) * LPAD + k] = (short)f2b(v.y);
        Wt[(n4 * 4 + 2) * LPAD + k] = (short)f2b(v.z);
        Wt[(n4 * 4 + 3) * LPAD + k] = (short)f2b(v.w);
    }
    if (t < 32) ((float4*)bl)[t] = ((const float4*)bias)[t];
    __syncthreads();

    int wave = t >> 6;
    int lane = t & 63;
    int quad = lane >> 4;
    int l16 = lane & 15;
    int rowbase = wave * 32;

    float4v acc[2][8];
    #pragma unroll
    for (int mt = 0; mt < 2; ++mt)
        #pragma unroll
        for (int nt = 0; nt < 8; ++nt)
            acc[mt][nt] = (float4v){0.f, 0.f, 0.f, 0.f};

    #pragma unroll
    for (int kc = 0; kc < 4; ++kc) {
        int koff = kc * 32 + quad * 8;
        short8 a0 = *(const short8*)&Al[(rowbase + l16) * LPAD + koff];
        short8 a1 = *(const short8*)&Al[(rowbase + 16 + l16) * LPAD + koff];
        #pragma unroll
        for (int nt = 0; nt < 8; ++nt) {
            short8 bfr = *(const short8*)&Wt[(nt * 16 + l16) * LPAD + koff];
            acc[0][nt] = __builtin_amdgcn_mfma_f32_16x16x32_bf16(a0, bfr, acc[0][nt], 0, 0, 0);
            acc[1][nt] = __builtin_amdgcn_mfma_f32_16x16x32_bf16(a1, bfr, acc[1][nt], 0, 0, 0);
        }
    }

    #pragma unroll
    for (int mt = 0; mt < 2; ++mt) {
        int rloc = rowbase + mt * 16 + quad * 4;
        #pragma unroll
        for (int nt = 0; nt < 8; ++nt) {
            int col = nt * 16 + l16;
            float bv = bl[col];
            #pragma unroll
            for (int r = 0; r < 4; ++r) {
                int grow = row0 + rloc + r;
                if (grow < M) {
                    float v = acc[mt][nt][r] + bv;
                    if (RELU) v = fmaxf(v, 0.f);
                    if (OUT_BF16)
                        ((unsigned short*)outv)[(size_t)grow * 128 + col] = f2b(v);
                    else
                        ((float*)outv)[(size_t)grow * 128 + col] = v;
                }
            }
        }
    }
}

extern "C" void kernel_launch(void* const* d_in, const int* in_sizes, int n_in,
                              void* d_out, int out_size, void* d_ws, size_t ws_size,
                              hipStream_t stream) {
    const float* x  = (const float*)d_in[0];
    const int*   ei = (const int*)d_in[1];
    const float* W1 = (const float*)d_in[2];
    const float* b1 = (const float*)d_in[3];
    const float* W2 = (const float*)d_in[4];
    const float* b2 = (const float*)d_in[5];
    float* out = (float*)d_out;

    // workspace layout (bytes):
    //   [0, 25,608,192)        cnt u16 matrix — dead after place
    //   [0, 12,800,000)        aggb (bf16) — alias over cnt, written by gather
    //   [25,700,000, 38,500,000) h bf16 — aliases rank @25.7e6 (6.4MB) and
    //                              srcs @32.1e6 (6.4MB), both dead before gemm1
    //   [38,500,000, 51,300,000) xb (bf16 x) — dead after gather
    //   [51,300,000 ...) deg, offsets, bsum, flag
    char* ws = (char*)d_ws;
    unsigned*       cntw    = (unsigned*)(ws);
    unsigned short* cnt16   = (unsigned short*)(ws);
    unsigned short* aggb    = (unsigned short*)(ws);
    unsigned short* hb      = (unsigned short*)(ws + 25700000);
    int*            rank    = (int*)  (ws + 25700000);
    int*            srcs    = (int*)  (ws + 32100000);
    unsigned short* xb      = (unsigned short*)(ws + 38500000);
    int*            deg     = (int*)  (ws + 51300000);
    int*            offsets = (int*)  (ws + 51500000);
    int*            bsum    = (int*)  (ws + 51700000);
    int*            flag    = (int*)  (ws + 51710000);

    const int NB_SCAN = (N_NODES + 511) / 512;  // 98

    k_cvt<<<(N_NODES * (D / 4) + 255) / 256, 256, 0, stream>>>(x, xb, ei, flag);
    k_hist_rank<<<NB_H, 1024, 0, stream>>>(ei, flag, cntw, rank);
    k_colscan_scan1<<<NB_SCAN, 512, 0, stream>>>(cnt16, deg, offsets, bsum);
    k_scan23<<<NB_SCAN, 512, 0, stream>>>(offsets, bsum, NB_SCAN);
    k_place<<<(N_EDGES + 1023) / 1024, 1024, 0, stream>>>(ei, flag, offsets, cnt16, rank, srcs);
    k_gather<<<(N_NODES + 3) / 4, 256, 0, stream>>>(x, xb, srcs, offsets, deg, aggb);

    int gblocks = (N_NODES + 127) / 128;  // 391
    k_gemm<1, 1><<<gblocks, 256, 0, stream>>>(aggb, W1, b1, hb, N_NODES);
    k_gemm<0, 0><<<gblocks, 256, 0, stream>>>(hb, W2, b2, out, N_NODES);
}